// Round 1
// baseline (1228.927 us; speedup 1.0000x reference)
//
#include <hip/hip_runtime.h>
#include <math.h>

#define B_      2
#define N_      4096
#define H_      1024
#define HEADS_  16
#define DH_     64
#define M_      256
#define NSPLIT  8

constexpr float NORMALIZER = 0.35355339059327373f; // 64^-0.25
constexpr float RATIO      = 0.0625f;              // 256^-0.5
constexpr float KEPS       = 1e-3f;

// ======================================================================
// SGEMM: C = A[M,K] @ B[N,K]^T + bias[N]   (einsum 'bni,oi->bno')
// 128x128 tile, BK=16, 256 threads, 8x8 microtile. z selects B/bias/C.
// ======================================================================
__global__ __launch_bounds__(256) void sgemm_bt_bias(
    const float* __restrict__ A,
    const float* __restrict__ B0, const float* __restrict__ B1, const float* __restrict__ B2,
    const float* __restrict__ bi0, const float* __restrict__ bi1, const float* __restrict__ bi2,
    float* __restrict__ C0, float* __restrict__ C1, float* __restrict__ C2,
    int M, int N, int K)
{
    const float* Bm = B0; const float* bias = bi0; float* C = C0;
    if (blockIdx.z == 1) { Bm = B1; bias = bi1; C = C1; }
    else if (blockIdx.z == 2) { Bm = B2; bias = bi2; C = C2; }

    __shared__ alignas(16) float As[16][132];
    __shared__ alignas(16) float Bs[16][132];

    const int t  = threadIdx.x;
    const int m0 = blockIdx.y * 128;
    const int n0 = blockIdx.x * 128;
    const int tm = (t & 15) * 8;
    const int tn = (t >> 4) * 8;

    float acc[8][8];
#pragma unroll
    for (int i = 0; i < 8; ++i)
#pragma unroll
        for (int j = 0; j < 8; ++j) acc[i][j] = 0.f;

    for (int k0 = 0; k0 < K; k0 += 16) {
#pragma unroll
        for (int i = 0; i < 2; ++i) {
            int f = t + i * 256;           // [0,512)
            int row = f >> 2;
            int kq  = (f & 3) * 4;
            float4 av = *(const float4*)(A  + (size_t)(m0 + row) * K + k0 + kq);
            As[kq+0][row] = av.x; As[kq+1][row] = av.y; As[kq+2][row] = av.z; As[kq+3][row] = av.w;
            float4 bv = *(const float4*)(Bm + (size_t)(n0 + row) * K + k0 + kq);
            Bs[kq+0][row] = bv.x; Bs[kq+1][row] = bv.y; Bs[kq+2][row] = bv.z; Bs[kq+3][row] = bv.w;
        }
        __syncthreads();
#pragma unroll
        for (int kk = 0; kk < 16; ++kk) {
            float4 a0 = *(const float4*)&As[kk][tm];
            float4 a1 = *(const float4*)&As[kk][tm+4];
            float4 b0 = *(const float4*)&Bs[kk][tn];
            float4 b1 = *(const float4*)&Bs[kk][tn+4];
            float ar[8] = {a0.x,a0.y,a0.z,a0.w,a1.x,a1.y,a1.z,a1.w};
            float br[8] = {b0.x,b0.y,b0.z,b0.w,b1.x,b1.y,b1.z,b1.w};
#pragma unroll
            for (int i = 0; i < 8; ++i)
#pragma unroll
                for (int j = 0; j < 8; ++j) acc[i][j] = fmaf(ar[i], br[j], acc[i][j]);
        }
        __syncthreads();
    }

    float bsr[8];
#pragma unroll
    for (int j = 0; j < 8; ++j) bsr[j] = bias[n0 + tn + j];
#pragma unroll
    for (int i = 0; i < 8; ++i) {
        float4 o0 = {acc[i][0]+bsr[0], acc[i][1]+bsr[1], acc[i][2]+bsr[2], acc[i][3]+bsr[3]};
        float4 o1 = {acc[i][4]+bsr[4], acc[i][5]+bsr[5], acc[i][6]+bsr[6], acc[i][7]+bsr[7]};
        float* crow = C + (size_t)(m0 + tm + i) * N + n0 + tn;
        *(float4*)(crow)     = o0;
        *(float4*)(crow + 4) = o1;
    }
}

// ======================================================================
// diag_k = -0.5*|k_row|^2 per (b,h,n); block-max partials for global stab.
// K layout: [b,n,h*64+d]; diag layout: [(b*16+h)*4096 + n]. 4 threads/row.
// ======================================================================
__global__ __launch_bounds__(256) void diag_kernel(
    const float* __restrict__ Kd, float* __restrict__ diag, float* __restrict__ partials)
{
    int gt = blockIdx.x * 256 + threadIdx.x;   // [0, 524288)
    int r  = gt >> 2;                          // row [0,131072)
    int q  = gt & 3;
    const float4* p = (const float4*)(Kd + (size_t)r * 64 + q * 16);
    float s = 0.f;
#pragma unroll
    for (int i = 0; i < 4; ++i) { float4 v = p[i]; s += v.x*v.x + v.y*v.y + v.z*v.z + v.w*v.w; }
    s += __shfl_xor(s, 1);
    s += __shfl_xor(s, 2);
    float d = -0.5f * s;
    if (q == 0) {
        int h = r & 15, bn = r >> 4;
        int n = bn & 4095, b = bn >> 12;
        diag[(((size_t)b * 16 + h) << 12) + n] = d;
    }
    __shared__ float red[256];
    red[threadIdx.x] = d;
    __syncthreads();
    for (int s2 = 128; s2 > 0; s2 >>= 1) {
        if (threadIdx.x < s2) red[threadIdx.x] = fmaxf(red[threadIdx.x], red[threadIdx.x + s2]);
        __syncthreads();
    }
    if (threadIdx.x == 0) partials[blockIdx.x] = red[0];
}

__global__ __launch_bounds__(256) void reduce_stab(
    const float* __restrict__ partials, float* __restrict__ stab, int n)
{
    float m = -3.0e38f;
    for (int i = threadIdx.x; i < n; i += 256) m = fmaxf(m, partials[i]);
    __shared__ float red[256];
    red[threadIdx.x] = m;
    __syncthreads();
    for (int s2 = 128; s2 > 0; s2 >>= 1) {
        if (threadIdx.x < s2) red[threadIdx.x] = fmaxf(red[threadIdx.x], red[threadIdx.x + s2]);
        __syncthreads();
    }
    if (threadIdx.x == 0) stab[0] = red[0];
}

// ======================================================================
// Context: ctx_part[k][bh][m][e] (e<64: sum_n kf[n,m]*v[n,e]; e==64: sum_n kf[n,m])
// kf computed on the fly: kf = RATIO*(exp(diag[n]-stab + NORM*k·proj_m)+eps)
// grid (NSPLIT, M_/64, B_*HEADS_), 256 threads. Deterministic slice partials.
// ======================================================================
__global__ __launch_bounds__(256) void ctx_kernel(
    const float* __restrict__ Kd, const float* __restrict__ Vd,
    const float* __restrict__ proj, const float* __restrict__ diag,
    const float* __restrict__ stabp, float* __restrict__ ctxp)
{
    __shared__ alignas(16) float projT[64][68];   // [d][m]
    __shared__ alignas(16) float kT[64][68];      // [d][n]; reused as kf[n][m] after dash
    __shared__ alignas(16) float vS[64][68];      // [n][e]
    __shared__ float kred[16][64];
    __shared__ float dg[64];

    const int t  = threadIdx.x;
    const int bh = blockIdx.z;
    const int b  = bh >> 4, h = bh & 15;
    const int m0 = blockIdx.y * 64;
    const int nbase = blockIdx.x * (N_ / NSPLIT);
    const float stab = *stabp;

#pragma unroll
    for (int i = 0; i < 4; ++i) {
        int f = i * 256 + t;
        int m = f >> 4, dq = (f & 15) * 4;
        float4 pv = *(const float4*)(proj + (size_t)(m0 + m) * DH_ + dq);
        projT[dq+0][m] = pv.x; projT[dq+1][m] = pv.y; projT[dq+2][m] = pv.z; projT[dq+3][m] = pv.w;
    }

    const int tn = (t & 15) * 4;   // dash: n   / ctx: m
    const int tm = (t >> 4) * 4;   // dash: m   / ctx: e

    float accC[4][4];
#pragma unroll
    for (int i = 0; i < 4; ++i)
#pragma unroll
        for (int j = 0; j < 4; ++j) accC[i][j] = 0.f;
    float accK[4] = {0.f, 0.f, 0.f, 0.f};

    const size_t rowbase = (size_t)b * N_ * H_ + (size_t)h * DH_;
    const float* diag_bh = diag + (size_t)bh * N_;

    for (int ni = 0; ni < N_ / NSPLIT; ni += 64) {
        const int n0 = nbase + ni;
        __syncthreads();   // prior iteration's reads of kT/vS complete
#pragma unroll
        for (int i = 0; i < 4; ++i) {
            int f = i * 256 + t;
            int n = f >> 4, dq = (f & 15) * 4;
            float4 kv = *(const float4*)(Kd + rowbase + (size_t)(n0 + n) * H_ + dq);
            kT[dq+0][n] = kv.x; kT[dq+1][n] = kv.y; kT[dq+2][n] = kv.z; kT[dq+3][n] = kv.w;
            float4 vv = *(const float4*)(Vd + rowbase + (size_t)(n0 + n) * H_ + dq);
            *(float4*)&vS[n][dq] = vv;
        }
        if (t < 64) dg[t] = diag_bh[n0 + t];
        __syncthreads();

        // dash phase: accD[i][j] = k[n=tn+i] . proj[m=tm+j]
        float accD[4][4];
#pragma unroll
        for (int i = 0; i < 4; ++i)
#pragma unroll
            for (int j = 0; j < 4; ++j) accD[i][j] = 0.f;
#pragma unroll 8
        for (int d = 0; d < 64; ++d) {
            float4 ka = *(const float4*)&kT[d][tn];
            float4 pa = *(const float4*)&projT[d][tm];
            float ar[4] = {ka.x, ka.y, ka.z, ka.w};
            float pr[4] = {pa.x, pa.y, pa.z, pa.w};
#pragma unroll
            for (int i = 0; i < 4; ++i)
#pragma unroll
                for (int j = 0; j < 4; ++j) accD[i][j] = fmaf(ar[i], pr[j], accD[i][j]);
        }
        float vals[4][4];
#pragma unroll
        for (int i = 0; i < 4; ++i) {
            float dgi = dg[tn + i] - stab;
#pragma unroll
            for (int j = 0; j < 4; ++j)
                vals[i][j] = RATIO * (expf(dgi + NORMALIZER * accD[i][j]) + KEPS);
        }
#pragma unroll
        for (int j = 0; j < 4; ++j)
            accK[j] += vals[0][j] + vals[1][j] + vals[2][j] + vals[3][j];

        __syncthreads();   // everyone done reading kT as [d][n]
#pragma unroll
        for (int i = 0; i < 4; ++i) {
            float4 w = {vals[i][0], vals[i][1], vals[i][2], vals[i][3]};
            *(float4*)&kT[tn + i][tm] = w;   // kf[n][m]
        }
        __syncthreads();

        // ctx accumulate: accC[m=tn+i][e=tm+j] += kf[n][m]*v[n][e]
#pragma unroll 8
        for (int n = 0; n < 64; ++n) {
            float4 kf = *(const float4*)&kT[n][tn];
            float4 vv = *(const float4*)&vS[n][tm];
            float kr[4] = {kf.x, kf.y, kf.z, kf.w};
            float vr[4] = {vv.x, vv.y, vv.z, vv.w};
#pragma unroll
            for (int i = 0; i < 4; ++i)
#pragma unroll
                for (int j = 0; j < 4; ++j) accC[i][j] = fmaf(kr[i], vr[j], accC[i][j]);
        }
    }

    // k_cumsum partial reduction across the 16 n-groups
#pragma unroll
    for (int j = 0; j < 4; ++j) kred[t & 15][tm + j] = accK[j];
    __syncthreads();

    const size_t cbase = ((size_t)blockIdx.x * (B_ * HEADS_) + bh) * (M_ * 65);
    if (t < 64) {
        float s = 0.f;
#pragma unroll
        for (int g = 0; g < 16; ++g) s += kred[g][t];
        ctxp[cbase + (size_t)(m0 + t) * 65 + 64] = s;
    }
#pragma unroll
    for (int i = 0; i < 4; ++i)
#pragma unroll
        for (int j = 0; j < 4; ++j)
            ctxp[cbase + (size_t)(m0 + tn + i) * 65 + (tm + j)] = accC[i][j];
}

// ======================================================================
// Out: for each (b,h), 64 q rows: qf = RATIO*(exp(NORM*q·proj_m)+eps) on the fly,
// out[n,e] = (sum_m qf*ctx[m,e]) / (sum_m qf*kcs[m]); writes attn [b,n,h*64+e].
// attn may alias Q (q tile staged to LDS first). grid (N_/64, B_*HEADS_).
// ======================================================================
__global__ __launch_bounds__(256) void out_kernel(
    const float* Qd, const float* __restrict__ proj,
    const float* __restrict__ ctxp, float* attn)
{
    __shared__ alignas(16) float qT[64][68];     // [d][n]
    __shared__ alignas(16) float pT[64][68];     // [d][m]; reused as qfT[m][n]
    __shared__ alignas(16) float ctxS[64][68];   // [m][e], e in [0,65)
    __shared__ float dred[16][64];
    __shared__ float dinv[64];

    const int t  = threadIdx.x;
    const int bh = blockIdx.y;
    const int b  = bh >> 4, h = bh & 15;
    const int n0 = blockIdx.x * 64;

    const size_t rowbase = (size_t)b * N_ * H_ + (size_t)h * DH_;
#pragma unroll
    for (int i = 0; i < 4; ++i) {
        int f = i * 256 + t;
        int n = f >> 4, dq = (f & 15) * 4;
        float4 qv = *(const float4*)(Qd + rowbase + (size_t)(n0 + n) * H_ + dq);
        qT[dq+0][n] = qv.x; qT[dq+1][n] = qv.y; qT[dq+2][n] = qv.z; qT[dq+3][n] = qv.w;
    }

    const int tn = (t & 15) * 4;   // n (dash + out)
    const int tm = (t >> 4) * 4;   // m (dash) / e (out)

    float accO[4][4];
#pragma unroll
    for (int i = 0; i < 4; ++i)
#pragma unroll
        for (int j = 0; j < 4; ++j) accO[i][j] = 0.f;
    float accDen[4] = {0.f, 0.f, 0.f, 0.f};

    const size_t SLICE = (size_t)(B_ * HEADS_) * M_ * 65;

    for (int mc = 0; mc < 4; ++mc) {
        const int m0 = mc * 64;
        __syncthreads();   // prior chunk reads complete
#pragma unroll
        for (int i = 0; i < 4; ++i) {
            int f = i * 256 + t;
            int m = f >> 4, dq = (f & 15) * 4;
            float4 pv = *(const float4*)(proj + (size_t)(m0 + m) * DH_ + dq);
            pT[dq+0][m] = pv.x; pT[dq+1][m] = pv.y; pT[dq+2][m] = pv.z; pT[dq+3][m] = pv.w;
        }
        for (int idx = t; idx < 64 * 65; idx += 256) {
            int ml = idx / 65, e = idx - ml * 65;
            size_t base = ((size_t)bh * M_ + m0 + ml) * 65 + e;
            float s = 0.f;
#pragma unroll
            for (int kk = 0; kk < NSPLIT; ++kk) s += ctxp[kk * SLICE + base];
            ctxS[ml][e] = s;
        }
        __syncthreads();

        // dash: q[n=tn+i] . proj[m=tm+j]
        float accD[4][4];
#pragma unroll
        for (int i = 0; i < 4; ++i)
#pragma unroll
            for (int j = 0; j < 4; ++j) accD[i][j] = 0.f;
#pragma unroll 8
        for (int d = 0; d < 64; ++d) {
            float4 qa = *(const float4*)&qT[d][tn];
            float4 pa = *(const float4*)&pT[d][tm];
            float qr[4] = {qa.x, qa.y, qa.z, qa.w};
            float pr[4] = {pa.x, pa.y, pa.z, pa.w};
#pragma unroll
            for (int i = 0; i < 4; ++i)
#pragma unroll
                for (int j = 0; j < 4; ++j) accD[i][j] = fmaf(qr[i], pr[j], accD[i][j]);
        }
        float kcsr[4] = {ctxS[tm+0][64], ctxS[tm+1][64], ctxS[tm+2][64], ctxS[tm+3][64]};
        float vals[4][4];
#pragma unroll
        for (int i = 0; i < 4; ++i)
#pragma unroll
            for (int j = 0; j < 4; ++j) {
                float qf = RATIO * (expf(NORMALIZER * accD[i][j]) + KEPS);
                vals[i][j] = qf;
                accDen[i] = fmaf(qf, kcsr[j], accDen[i]);
            }
        __syncthreads();   // done reading pT as [d][m]
#pragma unroll
        for (int j = 0; j < 4; ++j) {
            float4 w = {vals[0][j], vals[1][j], vals[2][j], vals[3][j]};
            *(float4*)&pT[tm + j][tn] = w;    // qfT[m][n]
        }
        __syncthreads();

        // out accumulate: accO[n=tn+i][e=tm+j] += qf[n][m]*ctx[m][e]
#pragma unroll 8
        for (int m = 0; m < 64; ++m) {
            float4 qa = *(const float4*)&pT[m][tn];
            float4 ca = *(const float4*)&ctxS[m][tm];
            float qr[4] = {qa.x, qa.y, qa.z, qa.w};
            float cr[4] = {ca.x, ca.y, ca.z, ca.w};
#pragma unroll
            for (int i = 0; i < 4; ++i)
#pragma unroll
                for (int j = 0; j < 4; ++j) accO[i][j] = fmaf(qr[i], cr[j], accO[i][j]);
        }
    }

    // denominator reduction across the 16 m-groups
#pragma unroll
    for (int i = 0; i < 4; ++i) dred[t >> 4][tn + i] = accDen[i];
    __syncthreads();
    if (t < 64) {
        float s = 0.f;
#pragma unroll
        for (int g = 0; g < 16; ++g) s += dred[g][t];
        dinv[t] = 1.f / s;
    }
    __syncthreads();

#pragma unroll
    for (int i = 0; i < 4; ++i) {
        float di = dinv[tn + i];
        float4 o = {accO[i][0]*di, accO[i][1]*di, accO[i][2]*di, accO[i][3]*di};
        *(float4*)(attn + rowbase + (size_t)(n0 + tn + i) * H_ + tm) = o;
    }
}

// ======================================================================
extern "C" void kernel_launch(void* const* d_in, const int* in_sizes, int n_in,
                              void* d_out, int out_size, void* d_ws, size_t ws_size,
                              hipStream_t stream) {
    const float* hs   = (const float*)d_in[0];
    const float* Wq   = (const float*)d_in[1];
    const float* bq   = (const float*)d_in[2];
    const float* Wk   = (const float*)d_in[3];
    const float* bk   = (const float*)d_in[4];
    const float* Wv   = (const float*)d_in[5];
    const float* bv   = (const float*)d_in[6];
    const float* Wo   = (const float*)d_in[7];
    const float* bo   = (const float*)d_in[8];
    const float* proj = (const float*)d_in[9];
    float* out = (float*)d_out;

    float* ws = (float*)d_ws;
    const size_t QSZ = (size_t)B_ * N_ * H_;          // 8388608
    float* Q     = ws;                                 // also attn (aliased)
    float* K     = ws + QSZ;
    float* V     = ws + 2 * QSZ;
    float* diag  = ws + 3 * QSZ;                       // 131072
    float* parts = diag + (size_t)B_ * HEADS_ * N_;    // 2048
    float* stab  = parts + 2048;                       // 1
    float* ctx   = stab + 1;                           // 8*32*256*65

    // 1) Q,K,V = hs @ W^T + b   (fused over z)
    sgemm_bt_bias<<<dim3(H_ / 128, (B_ * N_) / 128, 3), 256, 0, stream>>>(
        hs, Wq, Wk, Wv, bq, bk, bv, Q, K, V, B_ * N_, H_, H_);

    // 2) diag_k + global stabilizer
    diag_kernel<<<2048, 256, 0, stream>>>(K, diag, parts);
    reduce_stab<<<1, 256, 0, stream>>>(parts, stab, 2048);

    // 3) context partials (kf fused, k_cumsum as column 64)
    ctx_kernel<<<dim3(NSPLIT, M_ / 64, B_ * HEADS_), 256, 0, stream>>>(
        K, V, proj, diag, stab, ctx);

    // 4) out = (qf @ ctx) * d_inv  (qf fused); attn aliases Q
    out_kernel<<<dim3(N_ / 64, B_ * HEADS_), 256, 0, stream>>>(Q, proj, ctx, Q);

    // 5) final projection: out = attn @ Wo^T + bo
    sgemm_bt_bias<<<dim3(H_ / 128, (B_ * N_) / 128, 1), 256, 0, stream>>>(
        Q, Wo, Wo, Wo, bo, bo, bo, out, out, out, B_ * N_, H_, H_);
}

// Round 2
// 678.263 us; speedup vs baseline: 1.8119x; 1.8119x over previous
//
#include <hip/hip_runtime.h>
#include <math.h>

#define B_      2
#define N_      4096
#define H_      1024
#define HEADS_  16
#define DH_     64
#define M_      256
#define NSPLIT  8

constexpr float NORMALIZER = 0.35355339059327373f; // 64^-0.25
constexpr float RATIO      = 0.0625f;              // 256^-0.5
constexpr float KEPS       = 1e-3f;

typedef __bf16 bf16x8 __attribute__((ext_vector_type(8)));
typedef __bf16 bf16x4 __attribute__((ext_vector_type(4)));
typedef float  f32x4  __attribute__((ext_vector_type(4)));

// ======================================================================
// Split fp32 -> bf16 (hi, lo): x ~= hi + lo, ~16 mantissa bits retained.
// ======================================================================
__global__ __launch_bounds__(256) void split_bf16(
    const float* __restrict__ src, __bf16* __restrict__ hi, __bf16* __restrict__ lo)
{
    int i = blockIdx.x * 256 + threadIdx.x;     // one float4 per thread, grid sized exactly
    float4 v = ((const float4*)src)[i];
    float vv[4] = {v.x, v.y, v.z, v.w};
    bf16x4 h, l;
#pragma unroll
    for (int j = 0; j < 4; ++j) {
        __bf16 hh = (__bf16)vv[j];
        h[j] = hh;
        l[j] = (__bf16)(vv[j] - (float)hh);
    }
    ((bf16x4*)hi)[i] = h;
    ((bf16x4*)lo)[i] = l;
}

// 4 weight matrices (1024x1024 each) -> contiguous hi/lo segments (y selects)
__global__ __launch_bounds__(256) void split_w(
    const float* __restrict__ W0, const float* __restrict__ W1,
    const float* __restrict__ W2, const float* __restrict__ W3,
    __bf16* __restrict__ hi, __bf16* __restrict__ lo)
{
    const float* src = W0;
    if (blockIdx.y == 1) src = W1;
    else if (blockIdx.y == 2) src = W2;
    else if (blockIdx.y == 3) src = W3;
    int i = blockIdx.x * 256 + threadIdx.x;             // [0, 262144)
    size_t o = (size_t)blockIdx.y * 262144 + i;         // float4 units
    float4 v = ((const float4*)src)[i];
    float vv[4] = {v.x, v.y, v.z, v.w};
    bf16x4 h, l;
#pragma unroll
    for (int j = 0; j < 4; ++j) {
        __bf16 hh = (__bf16)vv[j];
        h[j] = hh;
        l[j] = (__bf16)(vv[j] - (float)hh);
    }
    ((bf16x4*)hi)[o] = h;
    ((bf16x4*)lo)[o] = l;
}

// ======================================================================
// Split-bf16 MFMA GEMM: C = A[M,1024] @ W[1024,1024]^T + bias, where
// A ~= Ah+Al, W ~= Wh+Wl (bf16). C = Ah*Wh + Al*Wh + Ah*Wl (3 MFMA products,
// fp32 accum -> ~fp32 accuracy). 128x128 tile, BK=32, 4 waves, 64x64/wave.
// LDS rows padded to 40 bf16 (80 B = 20 banks) -> only 2-way conflicts (free).
// ======================================================================
__global__ __launch_bounds__(256, 2) void gemm_mfma3(
    const __bf16* __restrict__ Ah, const __bf16* __restrict__ Al,
    const __bf16* __restrict__ Bh0, const __bf16* __restrict__ Bl0,
    const __bf16* __restrict__ Bh1, const __bf16* __restrict__ Bl1,
    const __bf16* __restrict__ Bh2, const __bf16* __restrict__ Bl2,
    const float* __restrict__ bi0, const float* __restrict__ bi1, const float* __restrict__ bi2,
    float* __restrict__ C0, float* __restrict__ C1, float* __restrict__ C2)
{
    const __bf16* Bh = Bh0; const __bf16* Bl = Bl0; const float* bias = bi0; float* C = C0;
    if (blockIdx.z == 1) { Bh = Bh1; Bl = Bl1; bias = bi1; C = C1; }
    else if (blockIdx.z == 2) { Bh = Bh2; Bl = Bl2; bias = bi2; C = C2; }

    __shared__ alignas(16) __bf16 AhS[128][40];
    __shared__ alignas(16) __bf16 AlS[128][40];
    __shared__ alignas(16) __bf16 BhS[128][40];
    __shared__ alignas(16) __bf16 BlS[128][40];

    const int t    = threadIdx.x;
    const int lane = t & 63;
    const int lm   = lane & 15;        // MFMA A/B row (m or n)
    const int lq   = lane >> 4;        // quad -> k-offset quad*8, D row quad*4+r
    const int wave = t >> 6;
    const int wm   = (wave >> 1) * 64;
    const int wn   = (wave & 1) * 64;
    const int m0   = blockIdx.y * 128;
    const int n0   = blockIdx.x * 128;
    const int K    = 1024;

    f32x4 acc[4][4];
#pragma unroll
    for (int i = 0; i < 4; ++i)
#pragma unroll
        for (int j = 0; j < 4; ++j) acc[i][j] = (f32x4){0.f, 0.f, 0.f, 0.f};

    for (int k0 = 0; k0 < K; k0 += 32) {
        __syncthreads();
#pragma unroll
        for (int i = 0; i < 2; ++i) {
            int idx = i * 256 + t;            // [0,512): 128 rows x 4 chunks of 8 bf16
            int row = idx >> 2;
            int c8  = (idx & 3) * 8;
            size_t ga = (size_t)(m0 + row) * K + k0 + c8;
            size_t gb = (size_t)(n0 + row) * K + k0 + c8;
            *(float4*)&AhS[row][c8] = *(const float4*)(Ah + ga);
            *(float4*)&AlS[row][c8] = *(const float4*)(Al + ga);
            *(float4*)&BhS[row][c8] = *(const float4*)(Bh + gb);
            *(float4*)&BlS[row][c8] = *(const float4*)(Bl + gb);
        }
        __syncthreads();

        bf16x8 bh[4], bl[4];
#pragma unroll
        for (int j = 0; j < 4; ++j) {
            bh[j] = *(const bf16x8*)&BhS[wn + j * 16 + lm][lq * 8];
            bl[j] = *(const bf16x8*)&BlS[wn + j * 16 + lm][lq * 8];
        }
#pragma unroll
        for (int i = 0; i < 4; ++i) {
            bf16x8 ah = *(const bf16x8*)&AhS[wm + i * 16 + lm][lq * 8];
            bf16x8 al = *(const bf16x8*)&AlS[wm + i * 16 + lm][lq * 8];
#pragma unroll
            for (int j = 0; j < 4; ++j) {
                acc[i][j] = __builtin_amdgcn_mfma_f32_16x16x32_bf16(ah, bh[j], acc[i][j], 0, 0, 0);
                acc[i][j] = __builtin_amdgcn_mfma_f32_16x16x32_bf16(al, bh[j], acc[i][j], 0, 0, 0);
                acc[i][j] = __builtin_amdgcn_mfma_f32_16x16x32_bf16(ah, bl[j], acc[i][j], 0, 0, 0);
            }
        }
    }

    float bsr[4];
#pragma unroll
    for (int j = 0; j < 4; ++j) bsr[j] = bias[n0 + wn + j * 16 + lm];
#pragma unroll
    for (int i = 0; i < 4; ++i)
#pragma unroll
        for (int j = 0; j < 4; ++j) {
            int col = n0 + wn + j * 16 + lm;
#pragma unroll
            for (int r = 0; r < 4; ++r) {
                int rowm = m0 + wm + i * 16 + lq * 4 + r;
                C[(size_t)rowm * 1024 + col] = acc[i][j][r] + bsr[j];
            }
        }
}

// ======================================================================
// diag_k = -0.5*|k_row|^2 per (b,h,n); block-max partials for global stab.
// ======================================================================
__global__ __launch_bounds__(256) void diag_kernel(
    const float* __restrict__ Kd, float* __restrict__ diag, float* __restrict__ partials)
{
    int gt = blockIdx.x * 256 + threadIdx.x;   // [0, 524288)
    int r  = gt >> 2;                          // row [0,131072)
    int q  = gt & 3;
    const float4* p = (const float4*)(Kd + (size_t)r * 64 + q * 16);
    float s = 0.f;
#pragma unroll
    for (int i = 0; i < 4; ++i) { float4 v = p[i]; s += v.x*v.x + v.y*v.y + v.z*v.z + v.w*v.w; }
    s += __shfl_xor(s, 1);
    s += __shfl_xor(s, 2);
    float d = -0.5f * s;
    if (q == 0) {
        int h = r & 15, bn = r >> 4;
        int n = bn & 4095, b = bn >> 12;
        diag[(((size_t)b * 16 + h) << 12) + n] = d;
    }
    __shared__ float red[256];
    red[threadIdx.x] = d;
    __syncthreads();
    for (int s2 = 128; s2 > 0; s2 >>= 1) {
        if (threadIdx.x < s2) red[threadIdx.x] = fmaxf(red[threadIdx.x], red[threadIdx.x + s2]);
        __syncthreads();
    }
    if (threadIdx.x == 0) partials[blockIdx.x] = red[0];
}

__global__ __launch_bounds__(256) void reduce_stab(
    const float* __restrict__ partials, float* __restrict__ stab, int n)
{
    float m = -3.0e38f;
    for (int i = threadIdx.x; i < n; i += 256) m = fmaxf(m, partials[i]);
    __shared__ float red[256];
    red[threadIdx.x] = m;
    __syncthreads();
    for (int s2 = 128; s2 > 0; s2 >>= 1) {
        if (threadIdx.x < s2) red[threadIdx.x] = fmaxf(red[threadIdx.x], red[threadIdx.x + s2]);
        __syncthreads();
    }
    if (threadIdx.x == 0) stab[0] = red[0];
}

// ======================================================================
// Context: ctx_part[k][bh][m][e] (e<64: sum_n kf[n,m]*v[n,e]; e==64: sum_n kf[n,m])
// ======================================================================
__global__ __launch_bounds__(256) void ctx_kernel(
    const float* __restrict__ Kd, const float* __restrict__ Vd,
    const float* __restrict__ proj, const float* __restrict__ diag,
    const float* __restrict__ stabp, float* __restrict__ ctxp)
{
    __shared__ alignas(16) float projT[64][68];   // [d][m]
    __shared__ alignas(16) float kT[64][68];      // [d][n]; reused as kf[n][m] after dash
    __shared__ alignas(16) float vS[64][68];      // [n][e]
    __shared__ float kred[16][64];
    __shared__ float dg[64];

    const int t  = threadIdx.x;
    const int bh = blockIdx.z;
    const int b  = bh >> 4, h = bh & 15;
    const int m0 = blockIdx.y * 64;
    const int nbase = blockIdx.x * (N_ / NSPLIT);
    const float stab = *stabp;

#pragma unroll
    for (int i = 0; i < 4; ++i) {
        int f = i * 256 + t;
        int m = f >> 4, dq = (f & 15) * 4;
        float4 pv = *(const float4*)(proj + (size_t)(m0 + m) * DH_ + dq);
        projT[dq+0][m] = pv.x; projT[dq+1][m] = pv.y; projT[dq+2][m] = pv.z; projT[dq+3][m] = pv.w;
    }

    const int tn = (t & 15) * 4;   // dash: n   / ctx: m
    const int tm = (t >> 4) * 4;   // dash: m   / ctx: e

    float accC[4][4];
#pragma unroll
    for (int i = 0; i < 4; ++i)
#pragma unroll
        for (int j = 0; j < 4; ++j) accC[i][j] = 0.f;
    float accK[4] = {0.f, 0.f, 0.f, 0.f};

    const size_t rowbase = (size_t)b * N_ * H_ + (size_t)h * DH_;
    const float* diag_bh = diag + (size_t)bh * N_;

    for (int ni = 0; ni < N_ / NSPLIT; ni += 64) {
        const int n0 = nbase + ni;
        __syncthreads();
#pragma unroll
        for (int i = 0; i < 4; ++i) {
            int f = i * 256 + t;
            int n = f >> 4, dq = (f & 15) * 4;
            float4 kv = *(const float4*)(Kd + rowbase + (size_t)(n0 + n) * H_ + dq);
            kT[dq+0][n] = kv.x; kT[dq+1][n] = kv.y; kT[dq+2][n] = kv.z; kT[dq+3][n] = kv.w;
            float4 vv = *(const float4*)(Vd + rowbase + (size_t)(n0 + n) * H_ + dq);
            *(float4*)&vS[n][dq] = vv;
        }
        if (t < 64) dg[t] = diag_bh[n0 + t];
        __syncthreads();

        float accD[4][4];
#pragma unroll
        for (int i = 0; i < 4; ++i)
#pragma unroll
            for (int j = 0; j < 4; ++j) accD[i][j] = 0.f;
#pragma unroll 8
        for (int d = 0; d < 64; ++d) {
            float4 ka = *(const float4*)&kT[d][tn];
            float4 pa = *(const float4*)&projT[d][tm];
            float ar[4] = {ka.x, ka.y, ka.z, ka.w};
            float pr[4] = {pa.x, pa.y, pa.z, pa.w};
#pragma unroll
            for (int i = 0; i < 4; ++i)
#pragma unroll
                for (int j = 0; j < 4; ++j) accD[i][j] = fmaf(ar[i], pr[j], accD[i][j]);
        }
        float vals[4][4];
#pragma unroll
        for (int i = 0; i < 4; ++i) {
            float dgi = dg[tn + i] - stab;
#pragma unroll
            for (int j = 0; j < 4; ++j)
                vals[i][j] = RATIO * (expf(dgi + NORMALIZER * accD[i][j]) + KEPS);
        }
#pragma unroll
        for (int j = 0; j < 4; ++j)
            accK[j] += vals[0][j] + vals[1][j] + vals[2][j] + vals[3][j];

        __syncthreads();
#pragma unroll
        for (int i = 0; i < 4; ++i) {
            float4 w = {vals[i][0], vals[i][1], vals[i][2], vals[i][3]};
            *(float4*)&kT[tn + i][tm] = w;   // kf[n][m]
        }
        __syncthreads();

#pragma unroll 8
        for (int n = 0; n < 64; ++n) {
            float4 kf = *(const float4*)&kT[n][tn];
            float4 vv = *(const float4*)&vS[n][tm];
            float kr[4] = {kf.x, kf.y, kf.z, kf.w};
            float vr[4] = {vv.x, vv.y, vv.z, vv.w};
#pragma unroll
            for (int i = 0; i < 4; ++i)
#pragma unroll
                for (int j = 0; j < 4; ++j) accC[i][j] = fmaf(kr[i], vr[j], accC[i][j]);
        }
    }

#pragma unroll
    for (int j = 0; j < 4; ++j) kred[t & 15][tm + j] = accK[j];
    __syncthreads();

    const size_t cbase = ((size_t)blockIdx.x * (B_ * HEADS_) + bh) * (M_ * 65);
    if (t < 64) {
        float s = 0.f;
#pragma unroll
        for (int g = 0; g < 16; ++g) s += kred[g][t];
        ctxp[cbase + (size_t)(m0 + t) * 65 + 64] = s;
    }
#pragma unroll
    for (int i = 0; i < 4; ++i)
#pragma unroll
        for (int j = 0; j < 4; ++j)
            ctxp[cbase + (size_t)(m0 + tn + i) * 65 + (tm + j)] = accC[i][j];
}

// ======================================================================
// Out: qf on the fly; out[n,e] = (sum_m qf*ctx[m,e]) / (sum_m qf*kcs[m]).
// Writes attn directly as split bf16 hi/lo (feeds the Wo MFMA GEMM).
// ======================================================================
__global__ __launch_bounds__(256) void out_kernel(
    const float* __restrict__ Qd, const float* __restrict__ proj,
    const float* __restrict__ ctxp,
    __bf16* __restrict__ attn_hi, __bf16* __restrict__ attn_lo)
{
    __shared__ alignas(16) float qT[64][68];     // [d][n]
    __shared__ alignas(16) float pT[64][68];     // [d][m]; reused as qfT[m][n]
    __shared__ alignas(16) float ctxS[64][68];   // [m][e], e in [0,65)
    __shared__ float dred[16][64];
    __shared__ float dinv[64];

    const int t  = threadIdx.x;
    const int bh = blockIdx.y;
    const int b  = bh >> 4, h = bh & 15;
    const int n0 = blockIdx.x * 64;

    const size_t rowbase = (size_t)b * N_ * H_ + (size_t)h * DH_;
#pragma unroll
    for (int i = 0; i < 4; ++i) {
        int f = i * 256 + t;
        int n = f >> 4, dq = (f & 15) * 4;
        float4 qv = *(const float4*)(Qd + rowbase + (size_t)(n0 + n) * H_ + dq);
        qT[dq+0][n] = qv.x; qT[dq+1][n] = qv.y; qT[dq+2][n] = qv.z; qT[dq+3][n] = qv.w;
    }

    const int tn = (t & 15) * 4;   // n
    const int tm = (t >> 4) * 4;   // m (dash) / e (out)

    float accO[4][4];
#pragma unroll
    for (int i = 0; i < 4; ++i)
#pragma unroll
        for (int j = 0; j < 4; ++j) accO[i][j] = 0.f;
    float accDen[4] = {0.f, 0.f, 0.f, 0.f};

    const size_t SLICE = (size_t)(B_ * HEADS_) * M_ * 65;

    for (int mc = 0; mc < 4; ++mc) {
        const int m0 = mc * 64;
        __syncthreads();
#pragma unroll
        for (int i = 0; i < 4; ++i) {
            int f = i * 256 + t;
            int m = f >> 4, dq = (f & 15) * 4;
            float4 pv = *(const float4*)(proj + (size_t)(m0 + m) * DH_ + dq);
            pT[dq+0][m] = pv.x; pT[dq+1][m] = pv.y; pT[dq+2][m] = pv.z; pT[dq+3][m] = pv.w;
        }
        for (int idx = t; idx < 64 * 65; idx += 256) {
            int ml = idx / 65, e = idx - ml * 65;
            size_t base = ((size_t)bh * M_ + m0 + ml) * 65 + e;
            float s = 0.f;
#pragma unroll
            for (int kk = 0; kk < NSPLIT; ++kk) s += ctxp[kk * SLICE + base];
            ctxS[ml][e] = s;
        }
        __syncthreads();

        float accD[4][4];
#pragma unroll
        for (int i = 0; i < 4; ++i)
#pragma unroll
            for (int j = 0; j < 4; ++j) accD[i][j] = 0.f;
#pragma unroll 8
        for (int d = 0; d < 64; ++d) {
            float4 qa = *(const float4*)&qT[d][tn];
            float4 pa = *(const float4*)&pT[d][tm];
            float qr[4] = {qa.x, qa.y, qa.z, qa.w};
            float pr[4] = {pa.x, pa.y, pa.z, pa.w};
#pragma unroll
            for (int i = 0; i < 4; ++i)
#pragma unroll
                for (int j = 0; j < 4; ++j) accD[i][j] = fmaf(qr[i], pr[j], accD[i][j]);
        }
        float kcsr[4] = {ctxS[tm+0][64], ctxS[tm+1][64], ctxS[tm+2][64], ctxS[tm+3][64]};
        float vals[4][4];
#pragma unroll
        for (int i = 0; i < 4; ++i)
#pragma unroll
            for (int j = 0; j < 4; ++j) {
                float qf = RATIO * (expf(NORMALIZER * accD[i][j]) + KEPS);
                vals[i][j] = qf;
                accDen[i] = fmaf(qf, kcsr[j], accDen[i]);
            }
        __syncthreads();
#pragma unroll
        for (int j = 0; j < 4; ++j) {
            float4 w = {vals[0][j], vals[1][j], vals[2][j], vals[3][j]};
            *(float4*)&pT[tm + j][tn] = w;    // qfT[m][n]
        }
        __syncthreads();

#pragma unroll 8
        for (int m = 0; m < 64; ++m) {
            float4 qa = *(const float4*)&pT[m][tn];
            float4 ca = *(const float4*)&ctxS[m][tm];
            float qr[4] = {qa.x, qa.y, qa.z, qa.w};
            float cr[4] = {ca.x, ca.y, ca.z, ca.w};
#pragma unroll
            for (int i = 0; i < 4; ++i)
#pragma unroll
                for (int j = 0; j < 4; ++j) accO[i][j] = fmaf(qr[i], cr[j], accO[i][j]);
        }
    }

#pragma unroll
    for (int i = 0; i < 4; ++i) dred[t >> 4][tn + i] = accDen[i];
    __syncthreads();
    if (t < 64) {
        float s = 0.f;
#pragma unroll
        for (int g = 0; g < 16; ++g) s += dred[g][t];
        dinv[t] = 1.f / s;
    }
    __syncthreads();

#pragma unroll
    for (int i = 0; i < 4; ++i) {
        float di = dinv[tn + i];
        bf16x4 oh, ol;
#pragma unroll
        for (int j = 0; j < 4; ++j) {
            float o = accO[i][j] * di;
            __bf16 hh = (__bf16)o;
            oh[j] = hh;
            ol[j] = (__bf16)(o - (float)hh);
        }
        size_t ob = rowbase + (size_t)(n0 + tn + i) * H_ + tm;
        *(bf16x4*)(attn_hi + ob) = oh;
        *(bf16x4*)(attn_lo + ob) = ol;
    }
}

// ======================================================================
extern "C" void kernel_launch(void* const* d_in, const int* in_sizes, int n_in,
                              void* d_out, int out_size, void* d_ws, size_t ws_size,
                              hipStream_t stream) {
    const float* hs   = (const float*)d_in[0];
    const float* Wq   = (const float*)d_in[1];
    const float* bq   = (const float*)d_in[2];
    const float* Wk   = (const float*)d_in[3];
    const float* bk   = (const float*)d_in[4];
    const float* Wv   = (const float*)d_in[5];
    const float* bv   = (const float*)d_in[6];
    const float* Wo   = (const float*)d_in[7];
    const float* bo   = (const float*)d_in[8];
    const float* proj = (const float*)d_in[9];
    float* out = (float*)d_out;

    float* ws = (float*)d_ws;
    const size_t QSZ = (size_t)B_ * N_ * H_;           // 8388608
    const size_t WSZ = (size_t)H_ * H_;                // 1048576
    const size_t CTXSZ = (size_t)NSPLIT * B_ * HEADS_ * M_ * 65;  // 4259840

    float* Q     = ws;                                 // fp32 Q
    float* K     = ws + QSZ;
    float* V     = ws + 2 * QSZ;
    float* diag  = ws + 3 * QSZ;                       // 131072
    float* parts = diag + (size_t)B_ * HEADS_ * N_;    // 2048
    float* stab  = parts + 2048;                       // 16 (pad)
    float* ctx   = stab + 16;                          // CTXSZ

    __bf16* hsH = (__bf16*)(ctx + CTXSZ);              // also attn_hi (aliased)
    __bf16* hsL = hsH + QSZ;                           // also attn_lo
    __bf16* WH  = hsL + QSZ;                           // 4 * WSZ
    __bf16* WL  = WH + 4 * WSZ;
    // segments: [Wq, Wk, Wv, Wo]
    __bf16 *WqH = WH,           *WkH = WH + WSZ, *WvH = WH + 2*WSZ, *WoH = WH + 3*WSZ;
    __bf16 *WqL = WL,           *WkL = WL + WSZ, *WvL = WL + 2*WSZ, *WoL = WL + 3*WSZ;

    // 0) split hs and weights into bf16 hi/lo
    split_bf16<<<QSZ / 4 / 256, 256, 0, stream>>>(hs, hsH, hsL);
    split_w<<<dim3(WSZ / 4 / 256, 4), 256, 0, stream>>>(Wq, Wk, Wv, Wo, WH, WL);

    // 1) Q,K,V = hs @ W^T + b   (split-bf16 MFMA, fused over z)
    gemm_mfma3<<<dim3(H_ / 128, (B_ * N_) / 128, 3), 256, 0, stream>>>(
        hsH, hsL, WqH, WqL, WkH, WkL, WvH, WvL, bq, bk, bv, Q, K, V);

    // 2) diag_k + global stabilizer
    diag_kernel<<<2048, 256, 0, stream>>>(K, diag, parts);
    reduce_stab<<<1, 256, 0, stream>>>(parts, stab, 2048);

    // 3) context partials (kf fused, k_cumsum as column 64)
    ctx_kernel<<<dim3(NSPLIT, M_ / 64, B_ * HEADS_), 256, 0, stream>>>(
        K, V, proj, diag, stab, ctx);

    // 4) out = (qf @ ctx) * d_inv; writes attn hi/lo bf16 (aliases hs hi/lo)
    out_kernel<<<dim3(N_ / 64, B_ * HEADS_), 256, 0, stream>>>(
        Q, proj, ctx, hsH, hsL);

    // 5) final projection: out = attn @ Wo^T + bo (split-bf16 MFMA)
    gemm_mfma3<<<dim3(H_ / 128, (B_ * N_) / 128, 1), 256, 0, stream>>>(
        hsH, hsL, WoH, WoL, WoH, WoL, WoH, WoL, bo, bo, bo, out, out, out);
}

// Round 3
// 544.050 us; speedup vs baseline: 2.2588x; 1.2467x over previous
//
#include <hip/hip_runtime.h>
#include <math.h>

#define B_      2
#define N_      4096
#define H_      1024
#define HEADS_  16
#define DH_     64
#define M_      256
#define NSPLIT  8
#define EPAD    80

constexpr float NORMALIZER = 0.35355339059327373f; // 64^-0.25
constexpr float RATIO      = 0.0625f;              // 256^-0.5
constexpr float KEPS       = 1e-3f;

typedef __bf16 bf16x8 __attribute__((ext_vector_type(8)));
typedef __bf16 bf16x4 __attribute__((ext_vector_type(4)));
typedef float  f32x4  __attribute__((ext_vector_type(4)));

// ======================================================================
// Split fp32 -> bf16 (hi, lo)
// ======================================================================
__global__ __launch_bounds__(256) void split_bf16(
    const float* __restrict__ src, __bf16* __restrict__ hi, __bf16* __restrict__ lo)
{
    int i = blockIdx.x * 256 + threadIdx.x;
    float4 v = ((const float4*)src)[i];
    float vv[4] = {v.x, v.y, v.z, v.w};
    bf16x4 h, l;
#pragma unroll
    for (int j = 0; j < 4; ++j) {
        __bf16 hh = (__bf16)vv[j];
        h[j] = hh;
        l[j] = (__bf16)(vv[j] - (float)hh);
    }
    ((bf16x4*)hi)[i] = h;
    ((bf16x4*)lo)[i] = l;
}

__global__ __launch_bounds__(256) void split_w(
    const float* __restrict__ W0, const float* __restrict__ W1,
    const float* __restrict__ W2, const float* __restrict__ W3,
    __bf16* __restrict__ hi, __bf16* __restrict__ lo)
{
    const float* src = W0;
    if (blockIdx.y == 1) src = W1;
    else if (blockIdx.y == 2) src = W2;
    else if (blockIdx.y == 3) src = W3;
    int i = blockIdx.x * 256 + threadIdx.x;
    size_t o = (size_t)blockIdx.y * 262144 + i;
    float4 v = ((const float4*)src)[i];
    float vv[4] = {v.x, v.y, v.z, v.w};
    bf16x4 h, l;
#pragma unroll
    for (int j = 0; j < 4; ++j) {
        __bf16 hh = (__bf16)vv[j];
        h[j] = hh;
        l[j] = (__bf16)(vv[j] - (float)hh);
    }
    ((bf16x4*)hi)[o] = h;
    ((bf16x4*)lo)[o] = l;
}

// ======================================================================
// Split-bf16 MFMA GEMM, C = A@W^T + bias. BF16OUT: write C as bf16 hi/lo.
// ======================================================================
template<bool BF16OUT>
__global__ __launch_bounds__(256, 2) void gemm_mfma3(
    const __bf16* __restrict__ Ah, const __bf16* __restrict__ Al,
    const __bf16* __restrict__ Bh0, const __bf16* __restrict__ Bl0,
    const __bf16* __restrict__ Bh1, const __bf16* __restrict__ Bl1,
    const __bf16* __restrict__ Bh2, const __bf16* __restrict__ Bl2,
    const float* __restrict__ bi0, const float* __restrict__ bi1, const float* __restrict__ bi2,
    float* __restrict__ C0,
    __bf16* __restrict__ Ch0, __bf16* __restrict__ Cl0,
    __bf16* __restrict__ Ch1, __bf16* __restrict__ Cl1,
    __bf16* __restrict__ Ch2, __bf16* __restrict__ Cl2)
{
    const __bf16* Bh = Bh0; const __bf16* Bl = Bl0; const float* bias = bi0;
    __bf16* Ch = Ch0; __bf16* Cl = Cl0;
    if (blockIdx.z == 1) { Bh = Bh1; Bl = Bl1; bias = bi1; Ch = Ch1; Cl = Cl1; }
    else if (blockIdx.z == 2) { Bh = Bh2; Bl = Bl2; bias = bi2; Ch = Ch2; Cl = Cl2; }

    __shared__ alignas(16) __bf16 AhS[128][40];
    __shared__ alignas(16) __bf16 AlS[128][40];
    __shared__ alignas(16) __bf16 BhS[128][40];
    __shared__ alignas(16) __bf16 BlS[128][40];

    const int t    = threadIdx.x;
    const int lane = t & 63;
    const int lm   = lane & 15;
    const int lq   = lane >> 4;
    const int wave = t >> 6;
    const int wm   = (wave >> 1) * 64;
    const int wn   = (wave & 1) * 64;
    const int m0   = blockIdx.y * 128;
    const int n0   = blockIdx.x * 128;
    const int K    = 1024;

    f32x4 acc[4][4];
#pragma unroll
    for (int i = 0; i < 4; ++i)
#pragma unroll
        for (int j = 0; j < 4; ++j) acc[i][j] = (f32x4){0.f, 0.f, 0.f, 0.f};

    for (int k0 = 0; k0 < K; k0 += 32) {
        __syncthreads();
#pragma unroll
        for (int i = 0; i < 2; ++i) {
            int idx = i * 256 + t;
            int row = idx >> 2;
            int c8  = (idx & 3) * 8;
            size_t ga = (size_t)(m0 + row) * K + k0 + c8;
            size_t gb = (size_t)(n0 + row) * K + k0 + c8;
            *(float4*)&AhS[row][c8] = *(const float4*)(Ah + ga);
            *(float4*)&AlS[row][c8] = *(const float4*)(Al + ga);
            *(float4*)&BhS[row][c8] = *(const float4*)(Bh + gb);
            *(float4*)&BlS[row][c8] = *(const float4*)(Bl + gb);
        }
        __syncthreads();

        bf16x8 bh[4], bl[4];
#pragma unroll
        for (int j = 0; j < 4; ++j) {
            bh[j] = *(const bf16x8*)&BhS[wn + j * 16 + lm][lq * 8];
            bl[j] = *(const bf16x8*)&BlS[wn + j * 16 + lm][lq * 8];
        }
#pragma unroll
        for (int i = 0; i < 4; ++i) {
            bf16x8 ah = *(const bf16x8*)&AhS[wm + i * 16 + lm][lq * 8];
            bf16x8 al = *(const bf16x8*)&AlS[wm + i * 16 + lm][lq * 8];
#pragma unroll
            for (int j = 0; j < 4; ++j) {
                acc[i][j] = __builtin_amdgcn_mfma_f32_16x16x32_bf16(ah, bh[j], acc[i][j], 0, 0, 0);
                acc[i][j] = __builtin_amdgcn_mfma_f32_16x16x32_bf16(al, bh[j], acc[i][j], 0, 0, 0);
                acc[i][j] = __builtin_amdgcn_mfma_f32_16x16x32_bf16(ah, bl[j], acc[i][j], 0, 0, 0);
            }
        }
    }

    float bsr[4];
#pragma unroll
    for (int j = 0; j < 4; ++j) bsr[j] = bias[n0 + wn + j * 16 + lm];
#pragma unroll
    for (int i = 0; i < 4; ++i)
#pragma unroll
        for (int r = 0; r < 4; ++r) {
            int rowm = m0 + wm + i * 16 + lq * 4 + r;
#pragma unroll
            for (int j = 0; j < 4; ++j) {
                int col = n0 + wn + j * 16 + lm;
                float o = acc[i][j][r] + bsr[j];
                if (BF16OUT) {
                    __bf16 hh = (__bf16)o;
                    Ch[(size_t)rowm * 1024 + col] = hh;
                    Cl[(size_t)rowm * 1024 + col] = (__bf16)(o - (float)hh);
                } else {
                    C0[(size_t)rowm * 1024 + col] = o;
                }
            }
        }
}

// ======================================================================
// diag_k from bf16 hi/lo K
// ======================================================================
__global__ __launch_bounds__(256) void diag_kernel(
    const __bf16* __restrict__ Kh, const __bf16* __restrict__ Kl,
    float* __restrict__ diag, float* __restrict__ partials)
{
    int gt = blockIdx.x * 256 + threadIdx.x;
    int r  = gt >> 2;
    int q  = gt & 3;
    const bf16x8* ph = (const bf16x8*)(Kh + (size_t)r * 64 + q * 16);
    const bf16x8* pl = (const bf16x8*)(Kl + (size_t)r * 64 + q * 16);
    float s = 0.f;
#pragma unroll
    for (int i = 0; i < 2; ++i) {
        bf16x8 vh = ph[i], vl = pl[i];
#pragma unroll
        for (int j = 0; j < 8; ++j) {
            float x = (float)vh[j] + (float)vl[j];
            s += x * x;
        }
    }
    s += __shfl_xor(s, 1);
    s += __shfl_xor(s, 2);
    float d = -0.5f * s;
    if (q == 0) {
        int h = r & 15, bn = r >> 4;
        int n = bn & 4095, b = bn >> 12;
        diag[(((size_t)b * 16 + h) << 12) + n] = d;
    }
    __shared__ float red[256];
    red[threadIdx.x] = d;
    __syncthreads();
    for (int s2 = 128; s2 > 0; s2 >>= 1) {
        if (threadIdx.x < s2) red[threadIdx.x] = fmaxf(red[threadIdx.x], red[threadIdx.x + s2]);
        __syncthreads();
    }
    if (threadIdx.x == 0) partials[blockIdx.x] = red[0];
}

__global__ __launch_bounds__(256) void reduce_stab(
    const float* __restrict__ partials, float* __restrict__ stab, int n)
{
    float m = -3.0e38f;
    for (int i = threadIdx.x; i < n; i += 256) m = fmaxf(m, partials[i]);
    __shared__ float red[256];
    red[threadIdx.x] = m;
    __syncthreads();
    for (int s2 = 128; s2 > 0; s2 >>= 1) {
        if (threadIdx.x < s2) red[threadIdx.x] = fmaxf(red[threadIdx.x], red[threadIdx.x + s2]);
        __syncthreads();
    }
    if (threadIdx.x == 0) stab[0] = red[0];
}

// ======================================================================
// ctx via MFMA. grid (NSPLIT, 2 m-halves, 32 bh). 4 waves, wave owns 32 m.
// dash: D[n64, m32/wave] = K@proj^T (3 split products, operands from global)
// exp -> kf bf16 hi/lo -> LDS transpose kfT[m][n] -> ctx += kfT @ vT[e][n]
// e=64 is ones (k_cumsum); e 65..79 zero pad. fp32 partials out [s][bh][e][m].
// ======================================================================
__global__ __launch_bounds__(256) void ctx_mfma(
    const __bf16* __restrict__ Kh, const __bf16* __restrict__ Kl,
    const __bf16* __restrict__ Vh, const __bf16* __restrict__ Vl,
    const __bf16* __restrict__ projH, const __bf16* __restrict__ projL,
    const float* __restrict__ diag, const float* __restrict__ stabp,
    float* __restrict__ ctxp)
{
    __shared__ alignas(16) char ldsbuf[59904];
    __shared__ float dg[64];
    __bf16* kfTh = (__bf16*)ldsbuf;              // [128][72]
    __bf16* kfTl = kfTh + 9216;                  // [128][72]
    __bf16* vTh  = kfTl + 9216;                  // [80][72]
    __bf16* vTl  = vTh + 5760;                   // [80][72]
    float*  ctxe = (float*)ldsbuf;               // [128][81] (epilogue alias)

    const int t    = threadIdx.x;
    const int lane = t & 63;
    const int w    = t >> 6;
    const int lm   = lane & 15;
    const int lq   = lane >> 4;
    const int bh   = blockIdx.z;
    const int b    = bh >> 4, h = bh & 15;
    const int mh   = blockIdx.y;
    const int slice = blockIdx.x;
    const int mwave = mh * 128 + w * 32;          // global m base for wave
    const float stab = stabp[0];
    const size_t rowbase = (size_t)b * N_ * H_ + (size_t)h * DH_;
    const float* diag_bh = diag + (size_t)bh * N_;

    // vT constant rows: e=64 -> ones (hi), e>64 -> zero
    for (int idx = t; idx < 16 * 72; idx += 256) {
        int e = 64 + idx / 72, n = idx % 72;
        vTh[e * 72 + n] = (e == 64 && n < 64) ? (__bf16)1.0f : (__bf16)0.0f;
        vTl[e * 72 + n] = (__bf16)0.0f;
    }

    // proj B-frags, register-cached for whole kernel: [mf][ks]
    bf16x8 ph[2][2], pl[2][2];
#pragma unroll
    for (int mf = 0; mf < 2; ++mf)
#pragma unroll
        for (int ks = 0; ks < 2; ++ks) {
            size_t pa = (size_t)(mwave + mf * 16 + lm) * 64 + ks * 32 + lq * 8;
            ph[mf][ks] = *(const bf16x8*)(projH + pa);
            pl[mf][ks] = *(const bf16x8*)(projL + pa);
        }

    f32x4 acc[2][5];
#pragma unroll
    for (int mf = 0; mf < 2; ++mf)
#pragma unroll
        for (int ef = 0; ef < 5; ++ef) acc[mf][ef] = (f32x4){0.f, 0.f, 0.f, 0.f};

    for (int tile = 0; tile < 8; ++tile) {
        const int n0 = slice * (N_ / NSPLIT) + tile * 64;
        __syncthreads();   // barrier A: prior GEMM reads of vT done

        // stage vT rows 0..63 (transpose V[n][d] -> vT[d][n])
        {
            int nl = t >> 2, dc = (t & 3) * 16;
            size_t va = rowbase + (size_t)(n0 + nl) * H_ + dc;
            bf16x8 v0 = *(const bf16x8*)(Vh + va);
            bf16x8 v1 = *(const bf16x8*)(Vh + va + 8);
            bf16x8 u0 = *(const bf16x8*)(Vl + va);
            bf16x8 u1 = *(const bf16x8*)(Vl + va + 8);
#pragma unroll
            for (int j = 0; j < 8; ++j) {
                vTh[(dc + j) * 72 + nl]     = v0[j];
                vTh[(dc + 8 + j) * 72 + nl] = v1[j];
                vTl[(dc + j) * 72 + nl]     = u0[j];
                vTl[(dc + 8 + j) * 72 + nl] = u1[j];
            }
        }
        if (t < 64) dg[t] = diag_bh[n0 + t] - stab;

        // dash MFMA (global operands, no LDS dependency)
        f32x4 dsh[4][2];
#pragma unroll
        for (int nf = 0; nf < 4; ++nf) {
#pragma unroll
            for (int mf = 0; mf < 2; ++mf) dsh[nf][mf] = (f32x4){0.f, 0.f, 0.f, 0.f};
            bf16x8 ah[2], al[2];
#pragma unroll
            for (int ks = 0; ks < 2; ++ks) {
                size_t ka = rowbase + (size_t)(n0 + nf * 16 + lm) * H_ + ks * 32 + lq * 8;
                ah[ks] = *(const bf16x8*)(Kh + ka);
                al[ks] = *(const bf16x8*)(Kl + ka);
            }
#pragma unroll
            for (int mf = 0; mf < 2; ++mf)
#pragma unroll
                for (int ks = 0; ks < 2; ++ks) {
                    dsh[nf][mf] = __builtin_amdgcn_mfma_f32_16x16x32_bf16(ah[ks], ph[mf][ks], dsh[nf][mf], 0, 0, 0);
                    dsh[nf][mf] = __builtin_amdgcn_mfma_f32_16x16x32_bf16(al[ks], ph[mf][ks], dsh[nf][mf], 0, 0, 0);
                    dsh[nf][mf] = __builtin_amdgcn_mfma_f32_16x16x32_bf16(ah[ks], pl[mf][ks], dsh[nf][mf], 0, 0, 0);
                }
        }

        __syncthreads();   // barrier B: vT + dg staged

        // exp -> kf bf16 hi/lo -> kfT (wave-private rows)
#pragma unroll
        for (int nf = 0; nf < 4; ++nf) {
            float4 dgv = *(const float4*)&dg[nf * 16 + lq * 4];
            float dga[4] = {dgv.x, dgv.y, dgv.z, dgv.w};
#pragma unroll
            for (int mf = 0; mf < 2; ++mf) {
                int mrow = w * 32 + mf * 16 + lm;   // block-local m row
#pragma unroll
                for (int r = 0; r < 4; ++r) {
                    float kf = RATIO * (__expf(dga[r] + NORMALIZER * dsh[nf][mf][r]) + KEPS);
                    __bf16 hh = (__bf16)kf;
                    int nloc = nf * 16 + lq * 4 + r;
                    kfTh[mrow * 72 + nloc] = hh;
                    kfTl[mrow * 72 + nloc] = (__bf16)(kf - (float)hh);
                }
            }
        }

        // ctx accumulate: acc[mf][ef] += kfT[m][n] @ vT[e][n]
#pragma unroll
        for (int ks = 0; ks < 2; ++ks) {
#pragma unroll
            for (int mf = 0; mf < 2; ++mf) {
                bf16x8 af = *(const bf16x8*)&kfTh[(w * 32 + mf * 16 + lm) * 72 + ks * 32 + lq * 8];
                bf16x8 afl = *(const bf16x8*)&kfTl[(w * 32 + mf * 16 + lm) * 72 + ks * 32 + lq * 8];
#pragma unroll
                for (int ef = 0; ef < 5; ++ef) {
                    bf16x8 bfh = *(const bf16x8*)&vTh[(ef * 16 + lm) * 72 + ks * 32 + lq * 8];
                    bf16x8 bfl = *(const bf16x8*)&vTl[(ef * 16 + lm) * 72 + ks * 32 + lq * 8];
                    acc[mf][ef] = __builtin_amdgcn_mfma_f32_16x16x32_bf16(af,  bfh, acc[mf][ef], 0, 0, 0);
                    acc[mf][ef] = __builtin_amdgcn_mfma_f32_16x16x32_bf16(afl, bfh, acc[mf][ef], 0, 0, 0);
                    acc[mf][ef] = __builtin_amdgcn_mfma_f32_16x16x32_bf16(af,  bfl, acc[mf][ef], 0, 0, 0);
                }
            }
        }
    }

    // epilogue: acc -> ctxe[m][e] (fp32, pad 81) -> coalesced global [s][bh][e][m]
    __syncthreads();
#pragma unroll
    for (int mf = 0; mf < 2; ++mf)
#pragma unroll
        for (int ef = 0; ef < 5; ++ef)
#pragma unroll
            for (int r = 0; r < 4; ++r) {
                int ml = w * 32 + mf * 16 + lq * 4 + r;
                int e  = ef * 16 + lm;
                ctxe[ml * 81 + e] = acc[mf][ef][r];
            }
    __syncthreads();
    const size_t SLICE = (size_t)(B_ * HEADS_) * EPAD * M_;
    const size_t obase = (size_t)slice * SLICE + (size_t)bh * EPAD * M_;
    for (int i = t; i < EPAD * 128; i += 256) {
        int e = i >> 7, ml = i & 127;
        ctxp[obase + (size_t)e * M_ + mh * 128 + ml] = ctxe[ml * 81 + e];
    }
}

// ======================================================================
// Reduce ctx partials over slices -> bf16 hi/lo ctxT[bh][e][m]
// ======================================================================
__global__ __launch_bounds__(256) void ctx_reduce(
    const float* __restrict__ ctxp, __bf16* __restrict__ ctxTh, __bf16* __restrict__ ctxTl)
{
    int idx = blockIdx.x * 256 + threadIdx.x;     // [0, 32*80*256)
    const size_t SLICE = (size_t)(B_ * HEADS_) * EPAD * M_;
    float s = 0.f;
#pragma unroll
    for (int k = 0; k < NSPLIT; ++k) s += ctxp[(size_t)k * SLICE + idx];
    __bf16 hh = (__bf16)s;
    ctxTh[idx] = hh;
    ctxTl[idx] = (__bf16)(s - (float)hh);
}

// ======================================================================
// out via MFMA. grid (N/64, 32 bh). 4 waves, wave owns 16 n rows. No barriers.
// dash D[n16, m64-chunk] -> qf -> wave-private LDS transpose -> acc += qf@ctxT.
// Column 64 of ctxT = k_cumsum -> denominator; shfl-broadcast; bf16 hi/lo out.
// ======================================================================
__global__ __launch_bounds__(256) void out_mfma(
    const __bf16* __restrict__ Qh, const __bf16* __restrict__ Ql,
    const __bf16* __restrict__ projH, const __bf16* __restrict__ projL,
    const __bf16* __restrict__ ctxTh, const __bf16* __restrict__ ctxTl,
    __bf16* __restrict__ attnH, __bf16* __restrict__ attnL)
{
    __shared__ alignas(16) __bf16 qfh[4][16][72];
    __shared__ alignas(16) __bf16 qfl[4][16][72];

    const int t    = threadIdx.x;
    const int lane = t & 63;
    const int w    = t >> 6;
    const int lm   = lane & 15;
    const int lq   = lane >> 4;
    const int bh   = blockIdx.y;
    const int b    = bh >> 4, h = bh & 15;
    const int nw   = blockIdx.x * 64 + w * 16;    // wave's n base
    const size_t rowbase = (size_t)b * N_ * H_ + (size_t)h * DH_;

    // A dash frags (q rows), loaded once
    bf16x8 qh_[2], ql_[2];
#pragma unroll
    for (int ks = 0; ks < 2; ++ks) {
        size_t qa = rowbase + (size_t)(nw + lm) * H_ + ks * 32 + lq * 8;
        qh_[ks] = *(const bf16x8*)(Qh + qa);
        ql_[ks] = *(const bf16x8*)(Ql + qa);
    }

    const __bf16* cth = ctxTh + (size_t)bh * EPAD * M_;
    const __bf16* ctl = ctxTl + (size_t)bh * EPAD * M_;

    f32x4 accO[5];
#pragma unroll
    for (int ef = 0; ef < 5; ++ef) accO[ef] = (f32x4){0.f, 0.f, 0.f, 0.f};

    for (int mc = 0; mc < 4; ++mc) {
        const int m0 = mc * 64;
        // dash
        f32x4 dsh[4];
#pragma unroll
        for (int mf = 0; mf < 4; ++mf) {
            dsh[mf] = (f32x4){0.f, 0.f, 0.f, 0.f};
#pragma unroll
            for (int ks = 0; ks < 2; ++ks) {
                size_t pa = (size_t)(m0 + mf * 16 + lm) * 64 + ks * 32 + lq * 8;
                bf16x8 ph = *(const bf16x8*)(projH + pa);
                bf16x8 pl = *(const bf16x8*)(projL + pa);
                dsh[mf] = __builtin_amdgcn_mfma_f32_16x16x32_bf16(qh_[ks], ph, dsh[mf], 0, 0, 0);
                dsh[mf] = __builtin_amdgcn_mfma_f32_16x16x32_bf16(ql_[ks], ph, dsh[mf], 0, 0, 0);
                dsh[mf] = __builtin_amdgcn_mfma_f32_16x16x32_bf16(qh_[ks], pl, dsh[mf], 0, 0, 0);
            }
        }
        // exp -> qf bf16 hi/lo -> wave-private LDS [n16][m64]
#pragma unroll
        for (int mf = 0; mf < 4; ++mf)
#pragma unroll
            for (int r = 0; r < 4; ++r) {
                float qf = RATIO * (__expf(NORMALIZER * dsh[mf][r]) + KEPS);
                __bf16 hh = (__bf16)qf;
                int nloc = lq * 4 + r;
                qfh[w][nloc][mf * 16 + lm] = hh;
                qfl[w][nloc][mf * 16 + lm] = (__bf16)(qf - (float)hh);
            }
        // out GEMM: acc += qf[n][m] @ ctxT[e][m]
#pragma unroll
        for (int ks = 0; ks < 2; ++ks) {
            bf16x8 af  = *(const bf16x8*)&qfh[w][lm][ks * 32 + lq * 8];
            bf16x8 afl = *(const bf16x8*)&qfl[w][lm][ks * 32 + lq * 8];
#pragma unroll
            for (int ef = 0; ef < 5; ++ef) {
                size_t ca = (size_t)(ef * 16 + lm) * M_ + m0 + ks * 32 + lq * 8;
                bf16x8 bfh = *(const bf16x8*)(cth + ca);
                bf16x8 bfl = *(const bf16x8*)(ctl + ca);
                accO[ef] = __builtin_amdgcn_mfma_f32_16x16x32_bf16(af,  bfh, accO[ef], 0, 0, 0);
                accO[ef] = __builtin_amdgcn_mfma_f32_16x16x32_bf16(afl, bfh, accO[ef], 0, 0, 0);
                accO[ef] = __builtin_amdgcn_mfma_f32_16x16x32_bf16(af,  bfl, accO[ef], 0, 0, 0);
            }
        }
    }

    // denominator: ctx column 64 -> accO[4] col (64 + lm); lm==0 holds den[row]
    float dinv[4];
#pragma unroll
    for (int r = 0; r < 4; ++r) {
        float den = __shfl(accO[4][r], lane & 48);
        dinv[r] = 1.f / den;
    }
#pragma unroll
    for (int ef = 0; ef < 4; ++ef)
#pragma unroll
        for (int r = 0; r < 4; ++r) {
            float o = accO[ef][r] * dinv[r];
            __bf16 hh = (__bf16)o;
            size_t oa = rowbase + (size_t)(nw + lq * 4 + r) * H_ + ef * 16 + lm;
            attnH[oa] = hh;
            attnL[oa] = (__bf16)(o - (float)hh);
        }
}

// ======================================================================
extern "C" void kernel_launch(void* const* d_in, const int* in_sizes, int n_in,
                              void* d_out, int out_size, void* d_ws, size_t ws_size,
                              hipStream_t stream) {
    const float* hs   = (const float*)d_in[0];
    const float* Wq   = (const float*)d_in[1];
    const float* bq   = (const float*)d_in[2];
    const float* Wk   = (const float*)d_in[3];
    const float* bk   = (const float*)d_in[4];
    const float* Wv   = (const float*)d_in[5];
    const float* bv   = (const float*)d_in[6];
    const float* Wo   = (const float*)d_in[7];
    const float* bo   = (const float*)d_in[8];
    const float* proj = (const float*)d_in[9];
    float* out = (float*)d_out;

    const size_t QSZ = (size_t)B_ * N_ * H_;           // 8388608
    const size_t WSZ = (size_t)H_ * H_;                // 1048576
    const size_t CTXT = (size_t)B_ * HEADS_ * EPAD * M_;  // 655360

    __bf16* Qh  = (__bf16*)d_ws;
    __bf16* Ql  = Qh + QSZ;
    __bf16* Kh  = Ql + QSZ;
    __bf16* Kl  = Kh + QSZ;
    __bf16* Vh  = Kl + QSZ;
    __bf16* Vl  = Vh + QSZ;
    __bf16* hsH = Vl + QSZ;      // aliased as attnH after hs consumed
    __bf16* hsL = hsH + QSZ;     // aliased as attnL
    __bf16* WH  = hsL + QSZ;
    __bf16* WL  = WH + 4 * WSZ;
    __bf16* projH = WL + 4 * WSZ;
    __bf16* projL = projH + (size_t)M_ * DH_;
    __bf16* ctxTh = projL + (size_t)M_ * DH_;
    __bf16* ctxTl = ctxTh + CTXT;
    float*  diag  = (float*)(ctxTl + CTXT);
    float*  parts = diag + (size_t)B_ * HEADS_ * N_;
    float*  stab  = parts + 2048;
    float*  ctxp  = stab + 16;

    __bf16 *WqH = WH, *WkH = WH + WSZ, *WvH = WH + 2*WSZ, *WoH = WH + 3*WSZ;
    __bf16 *WqL = WL, *WkL = WL + WSZ, *WvL = WL + 2*WSZ, *WoL = WL + 3*WSZ;

    // 0) splits
    split_bf16<<<QSZ / 4 / 256, 256, 0, stream>>>(hs, hsH, hsL);
    split_w<<<dim3(WSZ / 4 / 256, 4), 256, 0, stream>>>(Wq, Wk, Wv, Wo, WH, WL);
    split_bf16<<<(M_ * DH_) / 4 / 256, 256, 0, stream>>>(proj, projH, projL);

    // 1) Q,K,V = hs @ W^T + b  -> bf16 hi/lo
    gemm_mfma3<true><<<dim3(H_ / 128, (B_ * N_) / 128, 3), 256, 0, stream>>>(
        hsH, hsL, WqH, WqL, WkH, WkL, WvH, WvL, bq, bk, bv,
        nullptr, Qh, Ql, Kh, Kl, Vh, Vl);

    // 2) diag + global stabilizer
    diag_kernel<<<2048, 256, 0, stream>>>(Kh, Kl, diag, parts);
    reduce_stab<<<1, 256, 0, stream>>>(parts, stab, 2048);

    // 3) ctx partials (MFMA)
    ctx_mfma<<<dim3(NSPLIT, 2, B_ * HEADS_), 256, 0, stream>>>(
        Kh, Kl, Vh, Vl, projH, projL, diag, stab, ctxp);

    // 4) reduce partials -> bf16 ctxT
    ctx_reduce<<<(B_ * HEADS_ * EPAD * M_) / 256, 256, 0, stream>>>(ctxp, ctxTh, ctxTl);

    // 5) out (MFMA), writes attn bf16 hi/lo (aliases hs buffers)
    out_mfma<<<dim3(N_ / 64, B_ * HEADS_), 256, 0, stream>>>(
        Qh, Ql, projH, projL, ctxTh, ctxTl, hsH, hsL);

    // 6) final projection fp32 out
    gemm_mfma3<false><<<dim3(H_ / 128, (B_ * N_) / 128, 1), 256, 0, stream>>>(
        hsH, hsL, WoH, WoL, WoH, WoL, WoH, WoL, bo, bo, bo,
        out, nullptr, nullptr, nullptr, nullptr, nullptr, nullptr);
}